// Round 2
// baseline (341.187 us; speedup 1.0000x reference)
//
#include <hip/hip_runtime.h>

// VIF SSIM loss: per-11x11-block stats of three f32 images, SSIM score, mean.
// History: R1-R4 converged on a no-spill datapath (VGPR 76, 16.9KB LDS,
// float4 accumulators, end-of-loop l/r fold). R5 removed the same-address
// atomicAdd -> NO change (126us profiled / 339us timed), falsifying the
// atomic-serialization theory.
// R6 diagnosis: duration is invariant to (a) cache warmth (cold 190MB vs warm
// 65KB: same 126us), (b) occupancy ceiling (12 vs 24 waves/CU: same), and
// (c) reduction structure. VALUBusy 9% => ~12us of real VALU work; memory
// roofline ~15-60us. The only constant across all variants: 2048 workgroups.
// 126us/2048 = 61ns/WG => workgroup dispatch/setup serialization theory.
// R6 fix: 4 block-rows per WG -> grid 512x384. Datapath untouched. LDS zeroed
// once (write mapping identical each iteration; untouched slots stay 0);
// per-thread score accumulates across the 4 rows; one store per WG.

namespace {
constexpr int K      = 11;
constexpr int W      = 1408;
constexpr int H      = 1408;
constexpr int B      = 16;
constexpr int BPR    = W / K;     // 128 blocks per row
constexpr int BROWS  = H / K;     // 128 block rows
constexpr int CHUNKS = W / 4;     // 352 float4 chunks per image row
constexpr int RPW    = 4;         // block-rows per workgroup
constexpr int NWG    = B * BROWS / RPW;  // 512 workgroups in pass1
constexpr float C_C  = 0.0009f;
constexpr float INV_KK = 1.0f / (float)(K * K);
}

__device__ __forceinline__ void acc4(float4& a, const float4 v) {
    a.x += v.x; a.y += v.y; a.z += v.z; a.w += v.w;
}
__device__ __forceinline__ void fma4(float4& a, const float4 u, const float4 v) {
    a.x += u.x * v.x; a.y += u.y * v.y; a.z += u.z * v.z; a.w += u.w * v.w;
}

// Split a float4 column-sum into left-block / right-block contributions.
// nb = #leading components belonging to the left block (1..11; >=4 => all left).
__device__ __forceinline__ void split4(const float4 a, const int nb,
                                       float& l, float& r) {
    l = a.x;
    r = 0.f;
    if (nb > 1) l += a.y; else r += a.y;
    if (nb > 2) l += a.z; else r += a.z;
    if (nb > 3) l += a.w; else r += a.w;
}

// NOTE: no min-waves arg! (,6) clamps VGPR to 40 and spills ~1GB (R2/R3).
__global__ __launch_bounds__(384) void vif_pass1(
    const float* __restrict__ vis,
    const float* __restrict__ ir,
    const float* __restrict__ fus,
    double* __restrict__ partials)
{
    // Per-BLOCK partial sums: 8 quantities x 4 slots x 128 blocks = 16 KB.
    // Slot = chunk&3: the <=4 consecutive chunks overlapping a block get
    // distinct slots -> no atomics, deterministic (verified R2/R3, absmax 0).
    __shared__ float s[8][4][BPR];
    __shared__ float wsum[6];

    const int t = threadIdx.x;

    // Zero the partial-sum LDS ONCE. The write mapping below depends only on
    // t, so every iteration overwrites exactly the same slots; slots not
    // covered by any chunk stay 0 for all iterations.
    for (int i = t; i < 8 * 4 * BPR; i += 384) ((float*)s)[i] = 0.f;

    // Precompute per-thread fold geometry (depends only on t).
    const int bl = (4 * t) / K;            // left block index
    const int nb = K * (bl + 1) - 4 * t;   // #cols in left block
    const int sl = t & 3;

    float scoreacc = 0.0f;

    for (int g = 0; g < RPW; ++g) {
        const int vwg = blockIdx.x * RPW + g;   // virtual block-row id
        const int b   = vwg >> 7;               // batch
        const int br  = vwg & 127;              // block row

        __syncthreads();   // zero done (g=0) / prev phase2 reads done (g>0)

        if (t < CHUNKS) {
            const size_t base = (size_t)b * ((size_t)H * W)
                              + (size_t)br * K * W + (size_t)t * 4;
            float4 sv  = make_float4(0.f, 0.f, 0.f, 0.f);
            float4 sv2 = make_float4(0.f, 0.f, 0.f, 0.f);
            float4 si  = make_float4(0.f, 0.f, 0.f, 0.f);
            float4 si2 = make_float4(0.f, 0.f, 0.f, 0.f);
            float4 sf  = make_float4(0.f, 0.f, 0.f, 0.f);
            float4 sf2 = make_float4(0.f, 0.f, 0.f, 0.f);
            float4 svf = make_float4(0.f, 0.f, 0.f, 0.f);
            float4 sif = make_float4(0.f, 0.f, 0.f, 0.f);
#pragma unroll
            for (int r = 0; r < K; ++r) {
                const size_t o = base + (size_t)r * W;
                const float4 v = *(const float4*)(vis + o);
                const float4 i = *(const float4*)(ir  + o);
                const float4 f = *(const float4*)(fus + o);
                acc4(sv, v);
                fma4(sv2, v, v);
                acc4(si, i);
                fma4(si2, i, i);
                acc4(sf, f);
                fma4(sf2, f, f);
                fma4(svf, v, f);
                fma4(sif, i, f);
            }
            // Fold the 4 columns into per-block contributions.
            float l, r;
            split4(sv,  nb, l, r); s[0][sl][bl] = l; if (nb < 4) s[0][sl][bl + 1] = r;
            split4(sv2, nb, l, r); s[1][sl][bl] = l; if (nb < 4) s[1][sl][bl + 1] = r;
            split4(si,  nb, l, r); s[2][sl][bl] = l; if (nb < 4) s[2][sl][bl + 1] = r;
            split4(si2, nb, l, r); s[3][sl][bl] = l; if (nb < 4) s[3][sl][bl + 1] = r;
            split4(sf,  nb, l, r); s[4][sl][bl] = l; if (nb < 4) s[4][sl][bl + 1] = r;
            split4(sf2, nb, l, r); s[5][sl][bl] = l; if (nb < 4) s[5][sl][bl + 1] = r;
            split4(svf, nb, l, r); s[6][sl][bl] = l; if (nb < 4) s[6][sl][bl + 1] = r;
            split4(sif, nb, l, r); s[7][sl][bl] = l; if (nb < 4) s[7][sl][bl + 1] = r;
        }
        __syncthreads();

        // ---- Phase 2: fold 4 slots per block, compute score ----
        if (t < BPR) {
            float a[8];
#pragma unroll
            for (int q = 0; q < 8; ++q)   // lane-consecutive reads: conflict-free
                a[q] = s[q][0][t] + s[q][1][t] + s[q][2][t] + s[q][3][t];

            const float vm  = a[0] * INV_KK;
            const float vs2 = a[1] * INV_KK;
            const float im  = a[2] * INV_KK;
            const float is2 = a[3] * INV_KK;
            const float fm  = a[4] * INV_KK;
            const float fs2 = a[5] * INV_KK;
            const float vfm = a[6] * INV_KK;
            const float ifm = a[7] * INV_KK;

            const float vv = fabsf(vs2 - vm * vm);
            const float iv = fabsf(is2 - im * im);
            const float fv = fabsf(fs2 - fm * fm);
            const float vf_cov = vfm - vm * fm;
            const float if_cov = ifm - im * fm;

            const float l_vf = (2.f * vm * fm + C_C) / (vm * vm + fm * fm + C_C);
            const float l_if = (2.f * im * fm + C_C) / (im * im + fm * fm + C_C);
            const float s_vf = (vf_cov + C_C) / (vv + fv + C_C);
            const float s_if = (if_cov + C_C) / (iv + fv + C_C);

            scoreacc += (vm > im) ? (l_vf * s_vf) : (l_if * s_if);
        }
    }

    // ---- Reduce accumulated scores across the workgroup -> one plain store ----
    float score = scoreacc;
#pragma unroll
    for (int o = 32; o > 0; o >>= 1) score += __shfl_down(score, o, 64);
    if ((t & 63) == 0) wsum[t >> 6] = score;
    __syncthreads();
    if (t == 0) {
        float tot = 0.f;
#pragma unroll
        for (int wv = 0; wv < 6; ++wv) tot += wsum[wv];
        partials[blockIdx.x] = (double)tot;   // distinct slot per WG
    }
}

__global__ __launch_bounds__(64) void vif_finalize(
    const double* __restrict__ partials,
    float* __restrict__ out)
{
    const int t = threadIdx.x;
    double s = 0.0;
    for (int i = t; i < NWG; i += 64) s += partials[i];
#pragma unroll
    for (int o = 32; o > 0; o >>= 1) s += __shfl_down(s, o, 64);
    if (t == 0) {
        out[0] = 1.0f - (float)(s / (double)(B * BROWS * BPR));
    }
}

extern "C" void kernel_launch(void* const* d_in, const int* in_sizes, int n_in,
                              void* d_out, int out_size, void* d_ws, size_t ws_size,
                              hipStream_t stream) {
    const float* vis = (const float*)d_in[0];
    const float* ir  = (const float*)d_in[1];
    const float* fus = (const float*)d_in[2];
    float* out = (float*)d_out;
    double* partials = (double*)d_ws;   // 512 * 8B = 4 KB of workspace

    // No memset needed: every partials slot is written by pass1 every launch.
    vif_pass1<<<dim3(NWG), dim3(384), 0, stream>>>(vis, ir, fus, partials);
    vif_finalize<<<dim3(1), dim3(64), 0, stream>>>(partials, out);
}

// Round 3
// 340.987 us; speedup vs baseline: 1.0006x; 1.0006x over previous
//
#include <hip/hip_runtime.h>

// VIF SSIM loss: per-11x11-block stats of three f32 images, SSIM score, mean.
// History: R1-R4: no-spill datapath (float4 accums, LDS slot-fold), ~128us.
// R5: removed same-address f64 atomics -> null. R6: grid 2048->512 -> null.
// R7 diagnosis: duration invariant to warmth/occupancy/reduction/grid. Bytes
// consumed = 3*16*1408^2*4 = 380.6MB in ~130us = 2.93 TB/s READ traffic.
// Chip evidence (m13 copy = 3.15R+3.15W; RMSNorm 2.45R; LN ~2.6R) says the
// read-side streaming cap is ~3.0-3.15 TB/s (per-CU miss concurrency x
// ~700cy L3/HBM latency; L3 latency ~ HBM -> warmth invariance; extra waves
// don't add MLP once the per-CU miss buffer is full -> occupancy invariance).
// We are at ~93% of that cap. Remaining gap: duty-cycle hole -- zero loads in
// flight during fold/barrier/phase2 (compiler won't hoist loads across
// __syncthreads). R7: 4-row register ring software-pipelined across the whole
// 44-row stream INCLUDING across barriers. Accumulation order unchanged ->
// bitwise-identical result (absmax 0).

namespace {
constexpr int K      = 11;
constexpr int W      = 1408;
constexpr int H      = 1408;
constexpr int B      = 16;
constexpr int BPR    = W / K;     // 128 blocks per row
constexpr int BROWS  = H / K;     // 128 block rows
constexpr int CHUNKS = W / 4;     // 352 float4 chunks per image row
constexpr int RPW    = 4;         // block-rows per workgroup
constexpr int NWG    = B * BROWS / RPW;  // 512 workgroups in pass1
constexpr int DEPTH  = 4;         // row ring depth (12 float4 loads in flight)
constexpr float C_C  = 0.0009f;
constexpr float INV_KK = 1.0f / (float)(K * K);
}

__device__ __forceinline__ void acc4(float4& a, const float4 v) {
    a.x += v.x; a.y += v.y; a.z += v.z; a.w += v.w;
}
__device__ __forceinline__ void fma4(float4& a, const float4 u, const float4 v) {
    a.x += u.x * v.x; a.y += u.y * v.y; a.z += u.z * v.z; a.w += u.w * v.w;
}

// Split a float4 column-sum into left-block / right-block contributions.
__device__ __forceinline__ void split4(const float4 a, const int nb,
                                       float& l, float& r) {
    l = a.x;
    r = 0.f;
    if (nb > 1) l += a.y; else r += a.y;
    if (nb > 2) l += a.z; else r += a.z;
    if (nb > 3) l += a.w; else r += a.w;
}

// NOTE: no min-waves arg! (,6) clamped VGPR and spilled ~1GB (R2/R3).
// VGPR budget target <=128 so 2 WGs (12 waves) stay resident per CU.
__global__ __launch_bounds__(384) void vif_pass1(
    const float* __restrict__ vis,
    const float* __restrict__ ir,
    const float* __restrict__ fus,
    double* __restrict__ partials)
{
    // Per-BLOCK partial sums: 8 quantities x 4 slots x 128 blocks = 16 KB.
    // Slot = chunk&3: conflict-free deterministic scatter (verified, absmax 0).
    __shared__ float s[8][4][BPR];
    __shared__ float wsum[6];

    const int t = threadIdx.x;

    // Zero the partial-sum LDS ONCE (write mapping identical every iteration).
    for (int i = t; i < 8 * 4 * BPR; i += 384) ((float*)s)[i] = 0.f;

    // Per-thread fold geometry (depends only on t).
    const int bl = (4 * t) / K;            // left block index
    const int nb = K * (bl + 1) - 4 * t;   // #cols in left block
    const int sl = t & 3;

    // Per-iteration base offsets (uniform part + t*4); statically indexed.
    size_t gbase[RPW];
#pragma unroll
    for (int g = 0; g < RPW; ++g) {
        const int vwg = blockIdx.x * RPW + g;   // virtual block-row id
        gbase[g] = (size_t)(vwg >> 7) * ((size_t)H * W)
                 + (size_t)(vwg & 127) * (size_t)(K * W)
                 + (size_t)(4 * t);
    }

    // Row ring: DEPTH rows x 3 images in flight at all times, including
    // across the fold/barrier/phase2 boundary.
    float4 rv[DEPTH], ri[DEPTH], rf[DEPTH];

    if (t < CHUNKS) {
#pragma unroll
        for (int k = 0; k < DEPTH; ++k) {      // prologue: fill the ring
            const size_t o = gbase[k / K] + (size_t)((k % K) * W);
            rv[k] = *(const float4*)(vis + o);
            ri[k] = *(const float4*)(ir  + o);
            rf[k] = *(const float4*)(fus + o);
        }
    }

    float scoreacc = 0.0f;

#pragma unroll
    for (int g = 0; g < RPW; ++g) {
        if (t < CHUNKS) {
            float4 sv  = make_float4(0.f, 0.f, 0.f, 0.f);
            float4 sv2 = make_float4(0.f, 0.f, 0.f, 0.f);
            float4 si  = make_float4(0.f, 0.f, 0.f, 0.f);
            float4 si2 = make_float4(0.f, 0.f, 0.f, 0.f);
            float4 sf  = make_float4(0.f, 0.f, 0.f, 0.f);
            float4 sf2 = make_float4(0.f, 0.f, 0.f, 0.f);
            float4 svf = make_float4(0.f, 0.f, 0.f, 0.f);
            float4 sif = make_float4(0.f, 0.f, 0.f, 0.f);
#pragma unroll
            for (int r = 0; r < K; ++r) {
                const int k = g * K + r;        // linear row index, 0..43
                const int j = k & (DEPTH - 1);  // ring slot (compile-time)
                const float4 v  = rv[j];
                const float4 ii = ri[j];
                const float4 f  = rf[j];
                // Refill slot j with row k+DEPTH (next rows of this
                // iteration, or the first rows of the NEXT iteration --
                // these stay in flight across the barriers below).
                const int kn = k + DEPTH;
                if (kn < RPW * K) {             // compile-time guard
                    const size_t o = gbase[kn / K] + (size_t)((kn % K) * W);
                    rv[j] = *(const float4*)(vis + o);
                    ri[j] = *(const float4*)(ir  + o);
                    rf[j] = *(const float4*)(fus + o);
                }
                acc4(sv, v);
                fma4(sv2, v, v);
                acc4(si, ii);
                fma4(si2, ii, ii);
                acc4(sf, f);
                fma4(sf2, f, f);
                fma4(svf, v, f);
                fma4(sif, ii, f);
            }
            // Fold the 4 columns into per-block contributions.
            float l, r;
            split4(sv,  nb, l, r); s[0][sl][bl] = l; if (nb < 4) s[0][sl][bl + 1] = r;
            split4(sv2, nb, l, r); s[1][sl][bl] = l; if (nb < 4) s[1][sl][bl + 1] = r;
            split4(si,  nb, l, r); s[2][sl][bl] = l; if (nb < 4) s[2][sl][bl + 1] = r;
            split4(si2, nb, l, r); s[3][sl][bl] = l; if (nb < 4) s[3][sl][bl + 1] = r;
            split4(sf,  nb, l, r); s[4][sl][bl] = l; if (nb < 4) s[4][sl][bl + 1] = r;
            split4(sf2, nb, l, r); s[5][sl][bl] = l; if (nb < 4) s[5][sl][bl + 1] = r;
            split4(svf, nb, l, r); s[6][sl][bl] = l; if (nb < 4) s[6][sl][bl + 1] = r;
            split4(sif, nb, l, r); s[7][sl][bl] = l; if (nb < 4) s[7][sl][bl + 1] = r;
        }
        __syncthreads();   // fold writes (g) -> phase2 reads (g)

        // ---- Phase 2: fold 4 slots per block, compute score ----
        if (t < BPR) {
            float a[8];
#pragma unroll
            for (int q = 0; q < 8; ++q)   // lane-consecutive reads: conflict-free
                a[q] = s[q][0][t] + s[q][1][t] + s[q][2][t] + s[q][3][t];

            const float vm  = a[0] * INV_KK;
            const float vs2 = a[1] * INV_KK;
            const float im  = a[2] * INV_KK;
            const float is2 = a[3] * INV_KK;
            const float fm  = a[4] * INV_KK;
            const float fs2 = a[5] * INV_KK;
            const float vfm = a[6] * INV_KK;
            const float ifm = a[7] * INV_KK;

            const float vv = fabsf(vs2 - vm * vm);
            const float iv = fabsf(is2 - im * im);
            const float fv = fabsf(fs2 - fm * fm);
            const float vf_cov = vfm - vm * fm;
            const float if_cov = ifm - im * fm;

            const float l_vf = (2.f * vm * fm + C_C) / (vm * vm + fm * fm + C_C);
            const float l_if = (2.f * im * fm + C_C) / (im * im + fm * fm + C_C);
            const float s_vf = (vf_cov + C_C) / (vv + fv + C_C);
            const float s_if = (if_cov + C_C) / (iv + fv + C_C);

            scoreacc += (vm > im) ? (l_vf * s_vf) : (l_if * s_if);
        }
        __syncthreads();   // phase2 reads (g) -> fold writes (g+1)
    }

    // ---- Reduce accumulated scores across the workgroup -> one plain store ----
    float score = scoreacc;
#pragma unroll
    for (int o = 32; o > 0; o >>= 1) score += __shfl_down(score, o, 64);
    if ((t & 63) == 0) wsum[t >> 6] = score;
    __syncthreads();
    if (t == 0) {
        float tot = 0.f;
#pragma unroll
        for (int wv = 0; wv < 6; ++wv) tot += wsum[wv];
        partials[blockIdx.x] = (double)tot;   // distinct slot per WG
    }
}

__global__ __launch_bounds__(64) void vif_finalize(
    const double* __restrict__ partials,
    float* __restrict__ out)
{
    const int t = threadIdx.x;
    double s = 0.0;
    for (int i = t; i < NWG; i += 64) s += partials[i];
#pragma unroll
    for (int o = 32; o > 0; o >>= 1) s += __shfl_down(s, o, 64);
    if (t == 0) {
        out[0] = 1.0f - (float)(s / (double)(B * BROWS * BPR));
    }
}

extern "C" void kernel_launch(void* const* d_in, const int* in_sizes, int n_in,
                              void* d_out, int out_size, void* d_ws, size_t ws_size,
                              hipStream_t stream) {
    const float* vis = (const float*)d_in[0];
    const float* ir  = (const float*)d_in[1];
    const float* fus = (const float*)d_in[2];
    float* out = (float*)d_out;
    double* partials = (double*)d_ws;   // 512 * 8B = 4 KB of workspace

    // No memset needed: every partials slot is written by pass1 every launch.
    vif_pass1<<<dim3(NWG), dim3(384), 0, stream>>>(vis, ir, fus, partials);
    vif_finalize<<<dim3(1), dim3(64), 0, stream>>>(partials, out);
}

// Round 4
// 307.649 us; speedup vs baseline: 1.1090x; 1.1084x over previous
//
#include <hip/hip_runtime.h>

// VIF SSIM loss: per-11x11-block stats of three f32 images, SSIM score, mean.
// History: R1-R4: no-spill datapath (float4 accums, LDS slot-fold), ~128us.
// R5: no-atomic reduction -> null. R6: grid 2048->512 -> null. R7: 4-row
// register ring pipelined across barriers -> null (still ~130us).
// RETRACTION: R0's "warm-L3 replay same speed" was a misread -- those rows
// were the other PMC group (FETCH_SIZE=NaN). All real runs fetch ~190MB.
// R8 state of evidence: consumed read = 380.6MB (190MB HBM @ 1.47TB/s +
// ~190MB L3; inputs 380MB > 256MB L3 -> ~50% hit across iterations) in
// ~130us = 2.93 TB/s consumed, invariant to occupancy/grid/pipelining.
// Theory A: L3 fill+thrash path binds (no intra-dispatch reuse exists; L3
//   only helps across iterations). Fix: nt loads (evict-first, skip fill).
// Theory B: per-CU TCP fill-queue cap (~32 lines x 64B / ~430cy = 11.4
//   GB/s/CU x 256 = 2.93 TB/s). If B, nt does nothing -> ROOFLINE.
// R8 = the distinguishing experiment: __builtin_nontemporal_load on all
// three streams. Same loads, same order, same arithmetic -> absmax 0.

namespace {
constexpr int K      = 11;
constexpr int W      = 1408;
constexpr int H      = 1408;
constexpr int B      = 16;
constexpr int BPR    = W / K;     // 128 blocks per row
constexpr int BROWS  = H / K;     // 128 block rows
constexpr int CHUNKS = W / 4;     // 352 float4 chunks per image row
constexpr int RPW    = 4;         // block-rows per workgroup
constexpr int NWG    = B * BROWS / RPW;  // 512 workgroups in pass1
constexpr int DEPTH  = 4;         // row ring depth (12 float4 loads in flight)
constexpr float C_C  = 0.0009f;
constexpr float INV_KK = 1.0f / (float)(K * K);
}

typedef float vfloat4 __attribute__((ext_vector_type(4)));

// Non-temporal 16B load: global_load_dwordx4 with nt (evict-first / no L3
// pollution). Value-identical to a plain load.
__device__ __forceinline__ float4 ldnt4(const float* p) {
    const vfloat4 v = __builtin_nontemporal_load((const vfloat4*)p);
    return make_float4(v.x, v.y, v.z, v.w);
}

__device__ __forceinline__ void acc4(float4& a, const float4 v) {
    a.x += v.x; a.y += v.y; a.z += v.z; a.w += v.w;
}
__device__ __forceinline__ void fma4(float4& a, const float4 u, const float4 v) {
    a.x += u.x * v.x; a.y += u.y * v.y; a.z += u.z * v.z; a.w += u.w * v.w;
}

// Split a float4 column-sum into left-block / right-block contributions.
__device__ __forceinline__ void split4(const float4 a, const int nb,
                                       float& l, float& r) {
    l = a.x;
    r = 0.f;
    if (nb > 1) l += a.y; else r += a.y;
    if (nb > 2) l += a.z; else r += a.z;
    if (nb > 3) l += a.w; else r += a.w;
}

// NOTE: no min-waves arg! (,6) clamped VGPR and spilled ~1GB (R2/R3).
__global__ __launch_bounds__(384) void vif_pass1(
    const float* __restrict__ vis,
    const float* __restrict__ ir,
    const float* __restrict__ fus,
    double* __restrict__ partials)
{
    // Per-BLOCK partial sums: 8 quantities x 4 slots x 128 blocks = 16 KB.
    // Slot = chunk&3: conflict-free deterministic scatter (verified, absmax 0).
    __shared__ float s[8][4][BPR];
    __shared__ float wsum[6];

    const int t = threadIdx.x;

    // Zero the partial-sum LDS ONCE (write mapping identical every iteration).
    for (int i = t; i < 8 * 4 * BPR; i += 384) ((float*)s)[i] = 0.f;

    // Per-thread fold geometry (depends only on t).
    const int bl = (4 * t) / K;            // left block index
    const int nb = K * (bl + 1) - 4 * t;   // #cols in left block
    const int sl = t & 3;

    // Per-iteration base offsets (uniform part + t*4); statically indexed.
    size_t gbase[RPW];
#pragma unroll
    for (int g = 0; g < RPW; ++g) {
        const int vwg = blockIdx.x * RPW + g;   // virtual block-row id
        gbase[g] = (size_t)(vwg >> 7) * ((size_t)H * W)
                 + (size_t)(vwg & 127) * (size_t)(K * W)
                 + (size_t)(4 * t);
    }

    // Row ring: DEPTH rows x 3 images in flight at all times, including
    // across the fold/barrier/phase2 boundary.
    float4 rv[DEPTH], ri[DEPTH], rf[DEPTH];

    if (t < CHUNKS) {
#pragma unroll
        for (int k = 0; k < DEPTH; ++k) {      // prologue: fill the ring
            const size_t o = gbase[k / K] + (size_t)((k % K) * W);
            rv[k] = ldnt4(vis + o);
            ri[k] = ldnt4(ir  + o);
            rf[k] = ldnt4(fus + o);
        }
    }

    float scoreacc = 0.0f;

#pragma unroll
    for (int g = 0; g < RPW; ++g) {
        if (t < CHUNKS) {
            float4 sv  = make_float4(0.f, 0.f, 0.f, 0.f);
            float4 sv2 = make_float4(0.f, 0.f, 0.f, 0.f);
            float4 si  = make_float4(0.f, 0.f, 0.f, 0.f);
            float4 si2 = make_float4(0.f, 0.f, 0.f, 0.f);
            float4 sf  = make_float4(0.f, 0.f, 0.f, 0.f);
            float4 sf2 = make_float4(0.f, 0.f, 0.f, 0.f);
            float4 svf = make_float4(0.f, 0.f, 0.f, 0.f);
            float4 sif = make_float4(0.f, 0.f, 0.f, 0.f);
#pragma unroll
            for (int r = 0; r < K; ++r) {
                const int k = g * K + r;        // linear row index, 0..43
                const int j = k & (DEPTH - 1);  // ring slot (compile-time)
                const float4 v  = rv[j];
                const float4 ii = ri[j];
                const float4 f  = rf[j];
                // Refill slot j with row k+DEPTH; stays in flight across
                // the barriers below when kn crosses into iteration g+1.
                const int kn = k + DEPTH;
                if (kn < RPW * K) {             // compile-time guard
                    const size_t o = gbase[kn / K] + (size_t)((kn % K) * W);
                    rv[j] = ldnt4(vis + o);
                    ri[j] = ldnt4(ir  + o);
                    rf[j] = ldnt4(fus + o);
                }
                acc4(sv, v);
                fma4(sv2, v, v);
                acc4(si, ii);
                fma4(si2, ii, ii);
                acc4(sf, f);
                fma4(sf2, f, f);
                fma4(svf, v, f);
                fma4(sif, ii, f);
            }
            // Fold the 4 columns into per-block contributions.
            float l, r;
            split4(sv,  nb, l, r); s[0][sl][bl] = l; if (nb < 4) s[0][sl][bl + 1] = r;
            split4(sv2, nb, l, r); s[1][sl][bl] = l; if (nb < 4) s[1][sl][bl + 1] = r;
            split4(si,  nb, l, r); s[2][sl][bl] = l; if (nb < 4) s[2][sl][bl + 1] = r;
            split4(si2, nb, l, r); s[3][sl][bl] = l; if (nb < 4) s[3][sl][bl + 1] = r;
            split4(sf,  nb, l, r); s[4][sl][bl] = l; if (nb < 4) s[4][sl][bl + 1] = r;
            split4(sf2, nb, l, r); s[5][sl][bl] = l; if (nb < 4) s[5][sl][bl + 1] = r;
            split4(svf, nb, l, r); s[6][sl][bl] = l; if (nb < 4) s[6][sl][bl + 1] = r;
            split4(sif, nb, l, r); s[7][sl][bl] = l; if (nb < 4) s[7][sl][bl + 1] = r;
        }
        __syncthreads();   // fold writes (g) -> phase2 reads (g)

        // ---- Phase 2: fold 4 slots per block, compute score ----
        if (t < BPR) {
            float a[8];
#pragma unroll
            for (int q = 0; q < 8; ++q)   // lane-consecutive reads: conflict-free
                a[q] = s[q][0][t] + s[q][1][t] + s[q][2][t] + s[q][3][t];

            const float vm  = a[0] * INV_KK;
            const float vs2 = a[1] * INV_KK;
            const float im  = a[2] * INV_KK;
            const float is2 = a[3] * INV_KK;
            const float fm  = a[4] * INV_KK;
            const float fs2 = a[5] * INV_KK;
            const float vfm = a[6] * INV_KK;
            const float ifm = a[7] * INV_KK;

            const float vv = fabsf(vs2 - vm * vm);
            const float iv = fabsf(is2 - im * im);
            const float fv = fabsf(fs2 - fm * fm);
            const float vf_cov = vfm - vm * fm;
            const float if_cov = ifm - im * fm;

            const float l_vf = (2.f * vm * fm + C_C) / (vm * vm + fm * fm + C_C);
            const float l_if = (2.f * im * fm + C_C) / (im * im + fm * fm + C_C);
            const float s_vf = (vf_cov + C_C) / (vv + fv + C_C);
            const float s_if = (if_cov + C_C) / (iv + fv + C_C);

            scoreacc += (vm > im) ? (l_vf * s_vf) : (l_if * s_if);
        }
        __syncthreads();   // phase2 reads (g) -> fold writes (g+1)
    }

    // ---- Reduce accumulated scores across the workgroup -> one plain store ----
    float score = scoreacc;
#pragma unroll
    for (int o = 32; o > 0; o >>= 1) score += __shfl_down(score, o, 64);
    if ((t & 63) == 0) wsum[t >> 6] = score;
    __syncthreads();
    if (t == 0) {
        float tot = 0.f;
#pragma unroll
        for (int wv = 0; wv < 6; ++wv) tot += wsum[wv];
        partials[blockIdx.x] = (double)tot;   // distinct slot per WG
    }
}

__global__ __launch_bounds__(64) void vif_finalize(
    const double* __restrict__ partials,
    float* __restrict__ out)
{
    const int t = threadIdx.x;
    double s = 0.0;
    for (int i = t; i < NWG; i += 64) s += partials[i];
#pragma unroll
    for (int o = 32; o > 0; o >>= 1) s += __shfl_down(s, o, 64);
    if (t == 0) {
        out[0] = 1.0f - (float)(s / (double)(B * BROWS * BPR));
    }
}

extern "C" void kernel_launch(void* const* d_in, const int* in_sizes, int n_in,
                              void* d_out, int out_size, void* d_ws, size_t ws_size,
                              hipStream_t stream) {
    const float* vis = (const float*)d_in[0];
    const float* ir  = (const float*)d_in[1];
    const float* fus = (const float*)d_in[2];
    float* out = (float*)d_out;
    double* partials = (double*)d_ws;   // 512 * 8B = 4 KB of workspace

    // No memset needed: every partials slot is written by pass1 every launch.
    vif_pass1<<<dim3(NWG), dim3(384), 0, stream>>>(vis, ir, fus, partials);
    vif_finalize<<<dim3(1), dim3(64), 0, stream>>>(partials, out);
}